// Round 1
// baseline (282.385 us; speedup 1.0000x reference)
//
#include <hip/hip_runtime.h>

#define BS   256
#define RR   4
#define WW   128
#define NN   2048
#define HH   256
#define NT   512          // threads per block (8 waves)
#define KPT  4            // columns per thread = NN / NT
#define NWAVE (NT / 64)

__device__ __forceinline__ float wave_sum(float v) {
#pragma unroll
  for (int m = 32; m >= 1; m >>= 1) v += __shfl_xor(v, m, 64);
  return v;
}
__device__ __forceinline__ float wave_max(float v) {
#pragma unroll
  for (int m = 32; m >= 1; m >>= 1) v = fmaxf(v, __shfl_xor(v, m, 64));
  return v;
}

__device__ __forceinline__ float block_sum(float v, float* s_red) {
  const int tid = threadIdx.x;
  v = wave_sum(v);
  __syncthreads();
  if ((tid & 63) == 0) s_red[tid >> 6] = v;
  __syncthreads();
  float s = s_red[0];
#pragma unroll
  for (int i = 1; i < NWAVE; ++i) s += s_red[i];
  return s;
}

__device__ __forceinline__ float block_max(float v, float* s_red) {
  const int tid = threadIdx.x;
  v = wave_max(v);
  __syncthreads();
  if ((tid & 63) == 0) s_red[tid >> 6] = v;
  __syncthreads();
  float s = s_red[0];
#pragma unroll
  for (int i = 1; i < NWAVE; ++i) s = fmaxf(s, s_red[i]);
  return s;
}

__device__ __forceinline__ float gumbelf(float u) {
  return -logf(-logf(u + 1e-10f) + 1e-10f);
}

__global__ __launch_bounds__(NT) void explicit_mem_kernel(
    const float* __restrict__ k_r, const float* __restrict__ m_t,
    const float* __restrict__ hx, const float* __restrict__ memory,
    const float* __restrict__ usage, const float* __restrict__ read_weights,
    const float* __restrict__ Wg, const float* __restrict__ bg,
    const float* __restrict__ noise_write, const float* __restrict__ noise_read,
    float* __restrict__ m_read, float* __restrict__ mem_new,
    float* __restrict__ usage_new, float* __restrict__ read_wt_out,
    float* __restrict__ m_erased)
{
  __shared__ float s_wm[WW];          // tanh(m_t)
  __shared__ float s_rk[RR * WW];     // tanh(read keys)
  __shared__ float s_ut[NN];          // u_t
  __shared__ float s_rwt[RR * NN];    // read weights (for m_read pass)
  __shared__ float s_me[WW];          // m_erased accumulator
  __shared__ float s_red[NWAVE];      // reduction scratch
  __shared__ float s_rkinv[RR];       // 1/(||rk_r||+eps)

  const int b = blockIdx.x;
  const int tid = threadIdx.x;
  const int lane = tid & 63;
  const int wid = tid >> 6;

  // ---------- small-input staging ----------
  float gp = 0.f;
  if (tid < HH) gp = hx[(size_t)b * HH + tid] * Wg[tid];
  if (tid < WW) { s_wm[tid] = tanhf(m_t[(size_t)b * WW + tid]); s_me[tid] = 0.f; }
  s_rk[tid] = tanhf(k_r[(size_t)b * (RR * WW) + tid]);   // RR*WW == NT == 512
#pragma unroll
  for (int k = 0; k < KPT; ++k) {
    const int n = tid + k * NT;
    const size_t rb = (size_t)b * RR * NN;
    float s4 = read_weights[rb + n] + read_weights[rb + NN + n]
             + read_weights[rb + 2 * NN + n] + read_weights[rb + 3 * NN + n];
    s_ut[n] = 0.7f * usage[(size_t)b * NN + n] + 0.3f * s4;
  }

  // gamma = sigmoid(hx @ Wg + bg)     (block_sum barriers also publish LDS above)
  const float gamma = 1.f / (1.f + expf(-(block_sum(gp, s_red) + bg[0])));

  // 1/(||wm||+eps)
  float wmp = (tid < WW) ? s_wm[tid] * s_wm[tid] : 0.f;
  const float inv_wm = 1.f / (sqrtf(block_sum(wmp, s_red)) + 1e-8f);

  // per-read-key inverse norms (one wave per r)
  if (wid < RR) {
    float a = s_rk[wid * WW + lane];
    float c = s_rk[wid * WW + 64 + lane];
    float ss = wave_sum(a * a + c * c);
    if (lane == 0) s_rkinv[wid] = 1.f / (sqrtf(ss) + 1e-8f);
  }
  __syncthreads();

  // ---------- pass 1: column norms + write-key dot over original memory ----------
  const size_t base = (size_t)b * WW * NN;
  const float* Mb = memory + base;
  float cn[KPT], wd[KPT];
#pragma unroll
  for (int k = 0; k < KPT; ++k) { cn[k] = 0.f; wd[k] = 0.f; }
#pragma unroll 4
  for (int w = 0; w < WW; ++w) {
    const float wmw = s_wm[w];
    const float* row = Mb + (size_t)w * NN + tid;
#pragma unroll
    for (int k = 0; k < KPT; ++k) {
      float v = row[k * NT];
      cn[k] = fmaf(v, v, cn[k]);
      wd[k] = fmaf(wmw, v, wd[k]);
    }
  }

  // ---------- write softmax ----------
  float lg[KPT], mx = -1e30f;
#pragma unroll
  for (int k = 0; k < KPT; ++k) {
    const int n = tid + k * NT;
    float dist = wd[k] * inv_wm / (sqrtf(cn[k]) + 1e-8f);
    lg[k] = 1.f + dist - gamma * s_ut[n] + gumbelf(noise_write[(size_t)b * NN + n]);
    mx = fmaxf(mx, lg[k]);
  }
  mx = block_max(mx, s_red);
  float ex[KPT], es = 0.f;
#pragma unroll
  for (int k = 0; k < KPT; ++k) { ex[k] = expf(lg[k] - mx); es += ex[k]; }
  es = block_sum(es, s_red);
  const float inv_es = 1.f / es;
  float wtk[KPT], omw[KPT];
#pragma unroll
  for (int k = 0; k < KPT; ++k) {
    const int n = tid + k * NT;
    wtk[k] = ex[k] * inv_es;
    omw[k] = 1.f - wtk[k];
    usage_new[(size_t)b * NN + n] = s_ut[n] * omw[k];
  }

  // ---------- pass 2: mem_new write + new col norms + read-key dots + m_erased ----------
  float* MNb = mem_new + base;
  float cn2[KPT], rd[RR][KPT];
#pragma unroll
  for (int k = 0; k < KPT; ++k) {
    cn2[k] = 0.f;
#pragma unroll
    for (int r = 0; r < RR; ++r) rd[r][k] = 0.f;
  }
#pragma unroll 2
  for (int w = 0; w < WW; ++w) {
    const float wmw = s_wm[w];
    float rkw[RR];
#pragma unroll
    for (int r = 0; r < RR; ++r) rkw[r] = s_rk[r * WW + w];
    const size_t off = (size_t)w * NN + tid;
    float pme = 0.f;
#pragma unroll
    for (int k = 0; k < KPT; ++k) {
      float v = Mb[off + k * NT];
      float nv = fmaf(v, omw[k], wmw * wtk[k]);
      MNb[off + k * NT] = nv;
      cn2[k] = fmaf(nv, nv, cn2[k]);
#pragma unroll
      for (int r = 0; r < RR; ++r) rd[r][k] = fmaf(rkw[r], nv, rd[r][k]);
      pme = fmaf(wtk[k], v, pme);
    }
    pme = wave_sum(pme);
    if (lane == 0) atomicAdd(&s_me[w], pme);
  }
  __syncthreads();
  if (tid < WW) m_erased[(size_t)b * WW + tid] = s_me[tid];

  // ---------- read softmax ----------
  float inv_cn2[KPT];
#pragma unroll
  for (int k = 0; k < KPT; ++k) inv_cn2[k] = 1.f / (sqrtf(cn2[k]) + 1e-8f);
  const float invrk0 = s_rkinv[0], invrk1 = s_rkinv[1],
              invrk2 = s_rkinv[2], invrk3 = s_rkinv[3];
  const float invrk[RR] = { invrk0, invrk1, invrk2, invrk3 };

#pragma unroll
  for (int r = 0; r < RR; ++r) {
    float lr[KPT], mr = -1e30f;
#pragma unroll
    for (int k = 0; k < KPT; ++k) {
      const int n = tid + k * NT;
      float dr = rd[r][k] * invrk[r] * inv_cn2[k];
      lr[k] = dr + gumbelf(noise_read[((size_t)b * RR + r) * NN + n]);
      mr = fmaxf(mr, lr[k]);
    }
    mr = block_max(mr, s_red);
    float er[KPT], ers = 0.f;
#pragma unroll
    for (int k = 0; k < KPT; ++k) { er[k] = expf(lr[k] - mr); ers += er[k]; }
    ers = block_sum(ers, s_red);
    const float inv_ers = 1.f / ers;
#pragma unroll
    for (int k = 0; k < KPT; ++k) {
      const int n = tid + k * NT;
      float v = er[k] * inv_ers;
      s_rwt[r * NN + n] = v;
      read_wt_out[((size_t)b * RR + r) * NN + n] = v;
    }
  }
  __syncthreads();

  // ---------- pass 3: m_read = read_wt · mem_new^T (wave-parallel over w) ----------
#pragma unroll 1
  for (int wi = 0; wi < WW / NWAVE; ++wi) {   // 16 rows per wave
    const int w = wid * (WW / NWAVE) + wi;
    const float* rowp = MNb + (size_t)w * NN;
    float a0 = 0.f, a1 = 0.f, a2 = 0.f, a3 = 0.f;
#pragma unroll 4
    for (int j = 0; j < NN / 64; ++j) {
      const int n = lane + j * 64;
      float v = rowp[n];
      a0 = fmaf(s_rwt[n], v, a0);
      a1 = fmaf(s_rwt[NN + n], v, a1);
      a2 = fmaf(s_rwt[2 * NN + n], v, a2);
      a3 = fmaf(s_rwt[3 * NN + n], v, a3);
    }
    a0 = wave_sum(a0); a1 = wave_sum(a1); a2 = wave_sum(a2); a3 = wave_sum(a3);
    if (lane == 0) {
      float* o = m_read + (size_t)b * RR * WW;
      o[w] = a0; o[WW + w] = a1; o[2 * WW + w] = a2; o[3 * WW + w] = a3;
    }
  }
}

extern "C" void kernel_launch(void* const* d_in, const int* in_sizes, int n_in,
                              void* d_out, int out_size, void* d_ws, size_t ws_size,
                              hipStream_t stream) {
  (void)in_sizes; (void)n_in; (void)d_ws; (void)ws_size; (void)out_size;
  const float* k_r          = (const float*)d_in[0];
  const float* m_t          = (const float*)d_in[1];
  const float* hx           = (const float*)d_in[2];
  const float* memory       = (const float*)d_in[3];
  const float* usage        = (const float*)d_in[4];
  const float* read_weights = (const float*)d_in[5];
  const float* Wg           = (const float*)d_in[6];
  const float* bg           = (const float*)d_in[7];
  const float* noise_write  = (const float*)d_in[8];
  const float* noise_read   = (const float*)d_in[9];
  // d_in[10] (m_idx) and d_in[11] (seq_idx) are unused by the reference math.

  float* out       = (float*)d_out;
  float* m_read    = out;                                   // BS*RR*WW
  float* mem_new   = m_read + (size_t)BS * RR * WW;         // BS*WW*NN
  float* usage_new = mem_new + (size_t)BS * WW * NN;        // BS*NN
  float* read_wt   = usage_new + (size_t)BS * NN;           // BS*RR*NN
  float* m_erased  = read_wt + (size_t)BS * RR * NN;        // BS*WW

  explicit_mem_kernel<<<dim3(BS), dim3(NT), 0, stream>>>(
      k_r, m_t, hx, memory, usage, read_weights, Wg, bg,
      noise_write, noise_read,
      m_read, mem_new, usage_new, read_wt, m_erased);
}

// Round 2
// 214.803 us; speedup vs baseline: 1.3146x; 1.3146x over previous
//
#include <hip/hip_runtime.h>

#define BS   256
#define RR   4
#define WW   128
#define NN   2048
#define HH   256
#define NT   512          // threads per block (8 waves)
#define NWAVE (NT / 64)

__device__ __forceinline__ float wave_sum(float v) {
#pragma unroll
  for (int m = 32; m >= 1; m >>= 1) v += __shfl_xor(v, m, 64);
  return v;
}
__device__ __forceinline__ float wave_max(float v) {
#pragma unroll
  for (int m = 32; m >= 1; m >>= 1) v = fmaxf(v, __shfl_xor(v, m, 64));
  return v;
}

__device__ __forceinline__ float block_sum(float v, float* s_red) {
  const int tid = threadIdx.x;
  v = wave_sum(v);
  __syncthreads();
  if ((tid & 63) == 0) s_red[tid >> 6] = v;
  __syncthreads();
  float s = s_red[0];
#pragma unroll
  for (int i = 1; i < NWAVE; ++i) s += s_red[i];
  return s;
}

__device__ __forceinline__ float block_max(float v, float* s_red) {
  const int tid = threadIdx.x;
  v = wave_max(v);
  __syncthreads();
  if ((tid & 63) == 0) s_red[tid >> 6] = v;
  __syncthreads();
  float s = s_red[0];
#pragma unroll
  for (int i = 1; i < NWAVE; ++i) s = fmaxf(s, s_red[i]);
  return s;
}

// batched 4-channel block reductions (one LDS round-trip for all 4)
__device__ __forceinline__ void block_max4(float v[RR], float* s_red4) {
  const int tid = threadIdx.x, lane = tid & 63, wid = tid >> 6;
#pragma unroll
  for (int m = 32; m >= 1; m >>= 1) {
#pragma unroll
    for (int r = 0; r < RR; ++r) v[r] = fmaxf(v[r], __shfl_xor(v[r], m, 64));
  }
  __syncthreads();
  if (lane == 0) {
#pragma unroll
    for (int r = 0; r < RR; ++r) s_red4[wid * RR + r] = v[r];
  }
  __syncthreads();
#pragma unroll
  for (int r = 0; r < RR; ++r) {
    float s = s_red4[r];
#pragma unroll
    for (int i = 1; i < NWAVE; ++i) s = fmaxf(s, s_red4[i * RR + r]);
    v[r] = s;
  }
}

__device__ __forceinline__ void block_sum4(float v[RR], float* s_red4) {
  const int tid = threadIdx.x, lane = tid & 63, wid = tid >> 6;
#pragma unroll
  for (int m = 32; m >= 1; m >>= 1) {
#pragma unroll
    for (int r = 0; r < RR; ++r) v[r] += __shfl_xor(v[r], m, 64);
  }
  __syncthreads();
  if (lane == 0) {
#pragma unroll
    for (int r = 0; r < RR; ++r) s_red4[wid * RR + r] = v[r];
  }
  __syncthreads();
#pragma unroll
  for (int r = 0; r < RR; ++r) {
    float s = s_red4[r];
#pragma unroll
    for (int i = 1; i < NWAVE; ++i) s += s_red4[i * RR + r];
    v[r] = s;
  }
}

__device__ __forceinline__ float gumbelf(float u) {
  return -logf(-logf(u + 1e-10f) + 1e-10f);
}

__global__ __launch_bounds__(NT) void explicit_mem_kernel(
    const float* __restrict__ k_r, const float* __restrict__ m_t,
    const float* __restrict__ hx, const float* __restrict__ memory,
    const float* __restrict__ usage, const float* __restrict__ read_weights,
    const float* __restrict__ Wg, const float* __restrict__ bg,
    const float* __restrict__ noise_write, const float* __restrict__ noise_read,
    float* __restrict__ m_read, float* __restrict__ mem_new,
    float* __restrict__ usage_new, float* __restrict__ read_wt_out,
    float* __restrict__ m_erased)
{
  __shared__ float s_wm[WW];               // tanh(m_t)
  __shared__ float s_rk[RR * WW];          // tanh(read keys)
  __shared__ float s_rwt[RR * NN];         // read weights (for pass 3)
  __shared__ float s_me_part[WW * NWAVE];  // per-(row,wave) m_erased partials
  __shared__ float s_red[NWAVE * RR];      // reduction scratch
  __shared__ float s_rkinv[RR];            // 1/(||rk_r||+eps)

  const int b = blockIdx.x;
  const int tid = threadIdx.x;
  const int lane = tid & 63;
  const int wid = tid >> 6;
  const int c0 = 4 * tid;                  // this thread owns columns c0..c0+3

  // ---------- small-input staging ----------
  float gp = 0.f;
  if (tid < HH) gp = hx[(size_t)b * HH + tid] * Wg[tid];
  if (tid < WW) s_wm[tid] = tanhf(m_t[(size_t)b * WW + tid]);
  s_rk[tid] = tanhf(k_r[(size_t)b * (RR * WW) + tid]);   // RR*WW == NT == 512

  // u_t for this thread's 4 columns (registers only)
  float ut[4];
  {
    const size_t rb = (size_t)b * RR * NN;
    float4 u4 = *reinterpret_cast<const float4*>(usage + (size_t)b * NN + c0);
    float4 r0 = *reinterpret_cast<const float4*>(read_weights + rb + c0);
    float4 r1 = *reinterpret_cast<const float4*>(read_weights + rb + NN + c0);
    float4 r2 = *reinterpret_cast<const float4*>(read_weights + rb + 2 * NN + c0);
    float4 r3 = *reinterpret_cast<const float4*>(read_weights + rb + 3 * NN + c0);
    ut[0] = 0.7f * u4.x + 0.3f * (r0.x + r1.x + r2.x + r3.x);
    ut[1] = 0.7f * u4.y + 0.3f * (r0.y + r1.y + r2.y + r3.y);
    ut[2] = 0.7f * u4.z + 0.3f * (r0.z + r1.z + r2.z + r3.z);
    ut[3] = 0.7f * u4.w + 0.3f * (r0.w + r1.w + r2.w + r3.w);
  }

  // gamma = sigmoid(hx @ Wg + bg)   (block_sum barriers also publish LDS above)
  const float gamma = 1.f / (1.f + expf(-(block_sum(gp, s_red) + bg[0])));

  // 1/(||wm||+eps)
  float wmp = (tid < WW) ? s_wm[tid] * s_wm[tid] : 0.f;
  const float inv_wm = 1.f / (sqrtf(block_sum(wmp, s_red)) + 1e-8f);

  // per-read-key inverse norms (one wave per r)
  if (wid < RR) {
    float a = s_rk[wid * WW + lane];
    float c = s_rk[wid * WW + 64 + lane];
    float ss = wave_sum(a * a + c * c);
    if (lane == 0) s_rkinv[wid] = 1.f / (sqrtf(ss) + 1e-8f);
  }
  __syncthreads();

  // ---------- pass 1: column norms + write-key dot (float4, deep unroll) ----------
  const size_t base = (size_t)b * WW * NN;
  const float* Mb = memory + base;
  float cn[4] = {0.f, 0.f, 0.f, 0.f}, wd[4] = {0.f, 0.f, 0.f, 0.f};
#pragma unroll 8
  for (int w = 0; w < WW; ++w) {
    const float wmw = s_wm[w];
    float4 v = *reinterpret_cast<const float4*>(Mb + (size_t)w * NN + c0);
    cn[0] = fmaf(v.x, v.x, cn[0]); wd[0] = fmaf(wmw, v.x, wd[0]);
    cn[1] = fmaf(v.y, v.y, cn[1]); wd[1] = fmaf(wmw, v.y, wd[1]);
    cn[2] = fmaf(v.z, v.z, cn[2]); wd[2] = fmaf(wmw, v.z, wd[2]);
    cn[3] = fmaf(v.w, v.w, cn[3]); wd[3] = fmaf(wmw, v.w, wd[3]);
  }

  // ---------- write softmax ----------
  float lg[4], mx = -1e30f;
  {
    float4 nw = *reinterpret_cast<const float4*>(noise_write + (size_t)b * NN + c0);
    const float nwv[4] = {nw.x, nw.y, nw.z, nw.w};
#pragma unroll
    for (int j = 0; j < 4; ++j) {
      float dist = wd[j] * inv_wm / (sqrtf(cn[j]) + 1e-8f);
      lg[j] = 1.f + dist - gamma * ut[j] + gumbelf(nwv[j]);
      mx = fmaxf(mx, lg[j]);
    }
  }
  mx = block_max(mx, s_red);
  float ex[4], es = 0.f;
#pragma unroll
  for (int j = 0; j < 4; ++j) { ex[j] = expf(lg[j] - mx); es += ex[j]; }
  es = block_sum(es, s_red);
  const float inv_es = 1.f / es;
  float wtk[4], omw[4];
#pragma unroll
  for (int j = 0; j < 4; ++j) { wtk[j] = ex[j] * inv_es; omw[j] = 1.f - wtk[j]; }
  {
    float4 un;
    un.x = ut[0] * omw[0]; un.y = ut[1] * omw[1];
    un.z = ut[2] * omw[2]; un.w = ut[3] * omw[3];
    *reinterpret_cast<float4*>(usage_new + (size_t)b * NN + c0) = un;
  }

  // ---------- pass 2: mem_new + new col norms + read-key dots + m_erased partials ----------
  float* MNb = mem_new + base;
  float cn2[4] = {0.f, 0.f, 0.f, 0.f};
  float rd[RR][4];
#pragma unroll
  for (int r = 0; r < RR; ++r) {
#pragma unroll
    for (int j = 0; j < 4; ++j) rd[r][j] = 0.f;
  }
#pragma unroll 2
  for (int w0 = 0; w0 < WW; w0 += 4) {
    float pme[4];
#pragma unroll
    for (int i = 0; i < 4; ++i) {
      const int w = w0 + i;
      const float wmw = s_wm[w];
      const size_t off = (size_t)w * NN + c0;
      float4 v = *reinterpret_cast<const float4*>(Mb + off);
      float4 nv;
      nv.x = fmaf(v.x, omw[0], wmw * wtk[0]);
      nv.y = fmaf(v.y, omw[1], wmw * wtk[1]);
      nv.z = fmaf(v.z, omw[2], wmw * wtk[2]);
      nv.w = fmaf(v.w, omw[3], wmw * wtk[3]);
      *reinterpret_cast<float4*>(MNb + off) = nv;
      cn2[0] = fmaf(nv.x, nv.x, cn2[0]);
      cn2[1] = fmaf(nv.y, nv.y, cn2[1]);
      cn2[2] = fmaf(nv.z, nv.z, cn2[2]);
      cn2[3] = fmaf(nv.w, nv.w, cn2[3]);
#pragma unroll
      for (int r = 0; r < RR; ++r) {
        const float rkw = s_rk[r * WW + w];
        rd[r][0] = fmaf(rkw, nv.x, rd[r][0]);
        rd[r][1] = fmaf(rkw, nv.y, rd[r][1]);
        rd[r][2] = fmaf(rkw, nv.z, rd[r][2]);
        rd[r][3] = fmaf(rkw, nv.w, rd[r][3]);
      }
      float p = wtk[0] * v.x;
      p = fmaf(wtk[1], v.y, p);
      p = fmaf(wtk[2], v.z, p);
      p = fmaf(wtk[3], v.w, p);
      pme[i] = p;
    }
    // 4 independent overlapping wave reductions, no atomics
#pragma unroll
    for (int m = 32; m >= 1; m >>= 1) {
#pragma unroll
      for (int i = 0; i < 4; ++i) pme[i] += __shfl_xor(pme[i], m, 64);
    }
    if (lane == 0) {
#pragma unroll
      for (int i = 0; i < 4; ++i) s_me_part[(w0 + i) * NWAVE + wid] = pme[i];
    }
  }
  __syncthreads();
  if (tid < WW) {
    float s = 0.f;
#pragma unroll
    for (int i = 0; i < NWAVE; ++i) s += s_me_part[tid * NWAVE + i];
    m_erased[(size_t)b * WW + tid] = s;
  }

  // ---------- read softmax (batched 4-channel block reductions) ----------
  float inv_cn2[4];
#pragma unroll
  for (int j = 0; j < 4; ++j) inv_cn2[j] = 1.f / (sqrtf(cn2[j]) + 1e-8f);
  const float invrk[RR] = { s_rkinv[0], s_rkinv[1], s_rkinv[2], s_rkinv[3] };

  float lr[RR][4], mr[RR];
#pragma unroll
  for (int r = 0; r < RR; ++r) {
    float4 nr = *reinterpret_cast<const float4*>(
        noise_read + ((size_t)b * RR + r) * NN + c0);
    const float nrv[4] = {nr.x, nr.y, nr.z, nr.w};
    float m = -1e30f;
#pragma unroll
    for (int j = 0; j < 4; ++j) {
      float dr = rd[r][j] * invrk[r] * inv_cn2[j];
      lr[r][j] = dr + gumbelf(nrv[j]);
      m = fmaxf(m, lr[r][j]);
    }
    mr[r] = m;
  }
  block_max4(mr, s_red);
  float er[RR][4], ers[RR];
#pragma unroll
  for (int r = 0; r < RR; ++r) {
    float s = 0.f;
#pragma unroll
    for (int j = 0; j < 4; ++j) { er[r][j] = expf(lr[r][j] - mr[r]); s += er[r][j]; }
    ers[r] = s;
  }
  block_sum4(ers, s_red);
#pragma unroll
  for (int r = 0; r < RR; ++r) {
    const float inv_ers = 1.f / ers[r];
    float4 o;
    o.x = er[r][0] * inv_ers; o.y = er[r][1] * inv_ers;
    o.z = er[r][2] * inv_ers; o.w = er[r][3] * inv_ers;
    *reinterpret_cast<float4*>(&s_rwt[r * NN + c0]) = o;
    *reinterpret_cast<float4*>(read_wt_out + ((size_t)b * RR + r) * NN + c0) = o;
  }
  __syncthreads();

  // ---------- pass 3: m_read = read_wt · mem_new^T (wave-parallel rows, float4) ----------
#pragma unroll 1
  for (int wi = 0; wi < WW / NWAVE; ++wi) {   // 16 rows per wave
    const int w = wid * (WW / NWAVE) + wi;
    const float* rowp = MNb + (size_t)w * NN;
    float a[RR] = {0.f, 0.f, 0.f, 0.f};
#pragma unroll
    for (int j = 0; j < NN / (64 * 4); ++j) {   // 8 float4 per lane per row
      const int n = 4 * lane + j * 256;
      float4 v = *reinterpret_cast<const float4*>(rowp + n);
#pragma unroll
      for (int r = 0; r < RR; ++r) {
        float4 t = *reinterpret_cast<const float4*>(&s_rwt[r * NN + n]);
        a[r] = fmaf(t.x, v.x, a[r]);
        a[r] = fmaf(t.y, v.y, a[r]);
        a[r] = fmaf(t.z, v.z, a[r]);
        a[r] = fmaf(t.w, v.w, a[r]);
      }
    }
#pragma unroll
    for (int m = 32; m >= 1; m >>= 1) {
#pragma unroll
      for (int r = 0; r < RR; ++r) a[r] += __shfl_xor(a[r], m, 64);
    }
    if (lane == 0) {
      float* o = m_read + (size_t)b * RR * WW;
#pragma unroll
      for (int r = 0; r < RR; ++r) o[r * WW + w] = a[r];
    }
  }
}

extern "C" void kernel_launch(void* const* d_in, const int* in_sizes, int n_in,
                              void* d_out, int out_size, void* d_ws, size_t ws_size,
                              hipStream_t stream) {
  (void)in_sizes; (void)n_in; (void)d_ws; (void)ws_size; (void)out_size;
  const float* k_r          = (const float*)d_in[0];
  const float* m_t          = (const float*)d_in[1];
  const float* hx           = (const float*)d_in[2];
  const float* memory       = (const float*)d_in[3];
  const float* usage        = (const float*)d_in[4];
  const float* read_weights = (const float*)d_in[5];
  const float* Wg           = (const float*)d_in[6];
  const float* bg           = (const float*)d_in[7];
  const float* noise_write  = (const float*)d_in[8];
  const float* noise_read   = (const float*)d_in[9];
  // d_in[10] (m_idx) and d_in[11] (seq_idx) are unused by the reference math.

  float* out       = (float*)d_out;
  float* m_read    = out;                                   // BS*RR*WW
  float* mem_new   = m_read + (size_t)BS * RR * WW;         // BS*WW*NN
  float* usage_new = mem_new + (size_t)BS * WW * NN;        // BS*NN
  float* read_wt   = usage_new + (size_t)BS * NN;           // BS*RR*NN
  float* m_erased  = read_wt + (size_t)BS * RR * NN;        // BS*WW

  explicit_mem_kernel<<<dim3(BS), dim3(NT), 0, stream>>>(
      k_r, m_t, hx, memory, usage, read_weights, Wg, bg,
      noise_write, noise_read,
      m_read, mem_new, usage_new, read_wt, m_erased);
}

// Round 3
// 186.577 us; speedup vs baseline: 1.5135x; 1.1513x over previous
//
#include <hip/hip_runtime.h>

#define BS   256
#define RR   4
#define WW   128
#define NN   2048
#define HH   256
#define NT   512
#define WH   64            // rows per half-block (K1/K3)
#define NWAVE (NT / 64)

__device__ __forceinline__ float wave_sum(float v) {
#pragma unroll
  for (int m = 32; m >= 1; m >>= 1) v += __shfl_xor(v, m, 64);
  return v;
}
__device__ __forceinline__ float wave_max(float v) {
#pragma unroll
  for (int m = 32; m >= 1; m >>= 1) v = fmaxf(v, __shfl_xor(v, m, 64));
  return v;
}
__device__ __forceinline__ float block_sum(float v, float* s_red) {
  const int tid = threadIdx.x;
  v = wave_sum(v);
  __syncthreads();
  if ((tid & 63) == 0) s_red[tid >> 6] = v;
  __syncthreads();
  float s = s_red[0];
#pragma unroll
  for (int i = 1; i < NWAVE; ++i) s += s_red[i];
  return s;
}
__device__ __forceinline__ float block_max(float v, float* s_red) {
  const int tid = threadIdx.x;
  v = wave_max(v);
  __syncthreads();
  if ((tid & 63) == 0) s_red[tid >> 6] = v;
  __syncthreads();
  float s = s_red[0];
#pragma unroll
  for (int i = 1; i < NWAVE; ++i) s = fmaxf(s, s_red[i]);
  return s;
}
__device__ __forceinline__ void block_max4(float v[RR], float* s_red4) {
  const int tid = threadIdx.x, lane = tid & 63, wid = tid >> 6;
#pragma unroll
  for (int m = 32; m >= 1; m >>= 1) {
#pragma unroll
    for (int r = 0; r < RR; ++r) v[r] = fmaxf(v[r], __shfl_xor(v[r], m, 64));
  }
  __syncthreads();
  if (lane == 0) {
#pragma unroll
    for (int r = 0; r < RR; ++r) s_red4[wid * RR + r] = v[r];
  }
  __syncthreads();
#pragma unroll
  for (int r = 0; r < RR; ++r) {
    float s = s_red4[r];
#pragma unroll
    for (int i = 1; i < NWAVE; ++i) s = fmaxf(s, s_red4[i * RR + r]);
    v[r] = s;
  }
}
__device__ __forceinline__ void block_sum4(float v[RR], float* s_red4) {
  const int tid = threadIdx.x, lane = tid & 63, wid = tid >> 6;
#pragma unroll
  for (int m = 32; m >= 1; m >>= 1) {
#pragma unroll
    for (int r = 0; r < RR; ++r) v[r] += __shfl_xor(v[r], m, 64);
  }
  __syncthreads();
  if (lane == 0) {
#pragma unroll
    for (int r = 0; r < RR; ++r) s_red4[wid * RR + r] = v[r];
  }
  __syncthreads();
#pragma unroll
  for (int r = 0; r < RR; ++r) {
    float s = s_red4[r];
#pragma unroll
    for (int i = 1; i < NWAVE; ++i) s += s_red4[i * RR + r];
    v[r] = s;
  }
}
__device__ __forceinline__ float gumbelf(float u) {
  return -logf(-logf(u + 1e-10f) + 1e-10f);
}

// stats layout inside the mem_new output region (overwritten later by K3):
// comp 0=cn, 1=wd, 2..5=rdM[r];  index: ((rh*6+comp)*BS + b)*NN + n
#define STAT(base, rh, comp, b) ((base) + ((size_t)((rh)*6 + (comp)) * BS + (b)) * NN)

// ---------------- K1: per-column partial stats over a 64-row half ----------------
__global__ __launch_bounds__(NT, 4) void k1_stats(
    const float* __restrict__ k_r, const float* __restrict__ m_t,
    const float* __restrict__ memory, float* __restrict__ stats)
{
  __shared__ float s_wm[WH];
  __shared__ float s_rk[RR][WH];
  const int bid = blockIdx.x;
  const int b = bid >> 1, rh = bid & 1;
  const int tid = threadIdx.x;
  const int c0 = 4 * tid;

  if (tid < WH) {
    s_wm[tid] = tanhf(m_t[(size_t)b * WW + rh * WH + tid]);
  } else if (tid < WH + RR * WH) {
    const int i = tid - WH;            // 0..255: r = i>>6, w = i&63
    s_rk[i >> 6][i & 63] =
        tanhf(k_r[(size_t)b * RR * WW + (i >> 6) * WW + rh * WH + (i & 63)]);
  }
  __syncthreads();

  const float* Mb = memory + (size_t)b * WW * NN + (size_t)rh * WH * NN;
  float cn[4] = {0.f, 0.f, 0.f, 0.f}, wd[4] = {0.f, 0.f, 0.f, 0.f};
  float rdM[RR][4];
#pragma unroll
  for (int r = 0; r < RR; ++r) {
#pragma unroll
    for (int j = 0; j < 4; ++j) rdM[r][j] = 0.f;
  }
#pragma unroll 8
  for (int w = 0; w < WH; ++w) {
    float4 v = *reinterpret_cast<const float4*>(Mb + (size_t)w * NN + c0);
    const float wmw = s_wm[w];
    cn[0] = fmaf(v.x, v.x, cn[0]); wd[0] = fmaf(wmw, v.x, wd[0]);
    cn[1] = fmaf(v.y, v.y, cn[1]); wd[1] = fmaf(wmw, v.y, wd[1]);
    cn[2] = fmaf(v.z, v.z, cn[2]); wd[2] = fmaf(wmw, v.z, wd[2]);
    cn[3] = fmaf(v.w, v.w, cn[3]); wd[3] = fmaf(wmw, v.w, wd[3]);
#pragma unroll
    for (int r = 0; r < RR; ++r) {
      const float rkw = s_rk[r][w];
      rdM[r][0] = fmaf(rkw, v.x, rdM[r][0]);
      rdM[r][1] = fmaf(rkw, v.y, rdM[r][1]);
      rdM[r][2] = fmaf(rkw, v.z, rdM[r][2]);
      rdM[r][3] = fmaf(rkw, v.w, rdM[r][3]);
    }
  }
  float4 o;
  o.x = cn[0]; o.y = cn[1]; o.z = cn[2]; o.w = cn[3];
  *reinterpret_cast<float4*>(STAT(stats, rh, 0, b) + c0) = o;
  o.x = wd[0]; o.y = wd[1]; o.z = wd[2]; o.w = wd[3];
  *reinterpret_cast<float4*>(STAT(stats, rh, 1, b) + c0) = o;
#pragma unroll
  for (int r = 0; r < RR; ++r) {
    o.x = rdM[r][0]; o.y = rdM[r][1]; o.z = rdM[r][2]; o.w = rdM[r][3];
    *reinterpret_cast<float4*>(STAT(stats, rh, 2 + r, b) + c0) = o;
  }
}

// ---------------- K2: both softmaxes (one block per batch) ----------------
__global__ __launch_bounds__(NT) void k2_softmax(
    const float* __restrict__ k_r, const float* __restrict__ m_t,
    const float* __restrict__ hx, const float* __restrict__ usage,
    const float* __restrict__ read_weights, const float* __restrict__ Wg,
    const float* __restrict__ bg, const float* __restrict__ noise_write,
    const float* __restrict__ noise_read, const float* __restrict__ stats,
    float* __restrict__ wt_out, float* __restrict__ usage_new,
    float* __restrict__ read_wt_out)
{
  __shared__ float s_wm[WW];
  __shared__ float s_rk[RR * WW];
  __shared__ float s_red[NWAVE * RR];
  __shared__ float s_rkinv[RR], s_rkwm[RR];

  const int b = blockIdx.x;
  const int tid = threadIdx.x;
  const int lane = tid & 63;
  const int wid = tid >> 6;
  const int c0 = 4 * tid;

  float gp = 0.f;
  if (tid < HH) gp = hx[(size_t)b * HH + tid] * Wg[tid];
  if (tid < WW) s_wm[tid] = tanhf(m_t[(size_t)b * WW + tid]);
  s_rk[tid] = tanhf(k_r[(size_t)b * (RR * WW) + tid]);

  float ut[4];
  {
    const size_t rb = (size_t)b * RR * NN;
    float4 u4 = *reinterpret_cast<const float4*>(usage + (size_t)b * NN + c0);
    float4 r0 = *reinterpret_cast<const float4*>(read_weights + rb + c0);
    float4 r1 = *reinterpret_cast<const float4*>(read_weights + rb + NN + c0);
    float4 r2 = *reinterpret_cast<const float4*>(read_weights + rb + 2 * NN + c0);
    float4 r3 = *reinterpret_cast<const float4*>(read_weights + rb + 3 * NN + c0);
    ut[0] = 0.7f * u4.x + 0.3f * (r0.x + r1.x + r2.x + r3.x);
    ut[1] = 0.7f * u4.y + 0.3f * (r0.y + r1.y + r2.y + r3.y);
    ut[2] = 0.7f * u4.z + 0.3f * (r0.z + r1.z + r2.z + r3.z);
    ut[3] = 0.7f * u4.w + 0.3f * (r0.w + r1.w + r2.w + r3.w);
  }

  const float gamma = 1.f / (1.f + expf(-(block_sum(gp, s_red) + bg[0])));
  float wmp = (tid < WW) ? s_wm[tid] * s_wm[tid] : 0.f;
  const float wmss = block_sum(wmp, s_red);
  const float inv_wm = 1.f / (sqrtf(wmss) + 1e-8f);

  if (wid < RR) {
    const float a = s_rk[wid * WW + lane];
    const float c = s_rk[wid * WW + 64 + lane];
    const float wa = s_wm[lane], wc = s_wm[64 + lane];
    float ss = wave_sum(a * a + c * c);
    float sw = wave_sum(a * wa + c * wc);
    if (lane == 0) {
      s_rkinv[wid] = 1.f / (sqrtf(ss) + 1e-8f);
      s_rkwm[wid] = sw;
    }
  }
  __syncthreads();

  // combined column stats
  float cn[4], wd[4], rdM[RR][4];
  {
    float4 a0 = *reinterpret_cast<const float4*>(STAT(stats, 0, 0, b) + c0);
    float4 a1 = *reinterpret_cast<const float4*>(STAT(stats, 1, 0, b) + c0);
    cn[0] = a0.x + a1.x; cn[1] = a0.y + a1.y; cn[2] = a0.z + a1.z; cn[3] = a0.w + a1.w;
    float4 b0 = *reinterpret_cast<const float4*>(STAT(stats, 0, 1, b) + c0);
    float4 b1 = *reinterpret_cast<const float4*>(STAT(stats, 1, 1, b) + c0);
    wd[0] = b0.x + b1.x; wd[1] = b0.y + b1.y; wd[2] = b0.z + b1.z; wd[3] = b0.w + b1.w;
#pragma unroll
    for (int r = 0; r < RR; ++r) {
      float4 d0 = *reinterpret_cast<const float4*>(STAT(stats, 0, 2 + r, b) + c0);
      float4 d1 = *reinterpret_cast<const float4*>(STAT(stats, 1, 2 + r, b) + c0);
      rdM[r][0] = d0.x + d1.x; rdM[r][1] = d0.y + d1.y;
      rdM[r][2] = d0.z + d1.z; rdM[r][3] = d0.w + d1.w;
    }
  }

  // ---- write softmax ----
  float lg[4], mx = -1e30f;
  {
    float4 nw = *reinterpret_cast<const float4*>(noise_write + (size_t)b * NN + c0);
    const float nwv[4] = {nw.x, nw.y, nw.z, nw.w};
#pragma unroll
    for (int j = 0; j < 4; ++j) {
      float dist = wd[j] * inv_wm / (sqrtf(cn[j]) + 1e-8f);
      lg[j] = 1.f + dist - gamma * ut[j] + gumbelf(nwv[j]);
      mx = fmaxf(mx, lg[j]);
    }
  }
  mx = block_max(mx, s_red);
  float ex[4], es = 0.f;
#pragma unroll
  for (int j = 0; j < 4; ++j) { ex[j] = expf(lg[j] - mx); es += ex[j]; }
  es = block_sum(es, s_red);
  const float inv_es = 1.f / es;
  float wtk[4], omw[4];
#pragma unroll
  for (int j = 0; j < 4; ++j) { wtk[j] = ex[j] * inv_es; omw[j] = 1.f - wtk[j]; }
  {
    float4 un, wo;
    un.x = ut[0] * omw[0]; un.y = ut[1] * omw[1];
    un.z = ut[2] * omw[2]; un.w = ut[3] * omw[3];
    *reinterpret_cast<float4*>(usage_new + (size_t)b * NN + c0) = un;
    wo.x = wtk[0]; wo.y = wtk[1]; wo.z = wtk[2]; wo.w = wtk[3];
    *reinterpret_cast<float4*>(wt_out + (size_t)b * NN + c0) = wo;
  }

  // ---- read softmax (analytic stats of mem_new) ----
  const float invrk[RR] = { s_rkinv[0], s_rkinv[1], s_rkinv[2], s_rkinv[3] };
  const float rkwm[RR]  = { s_rkwm[0], s_rkwm[1], s_rkwm[2], s_rkwm[3] };
  float inv_cn2[4];
#pragma unroll
  for (int j = 0; j < 4; ++j) {
    float cn2 = omw[j] * omw[j] * cn[j]
              + 2.f * omw[j] * wtk[j] * wd[j]
              + wtk[j] * wtk[j] * wmss;
    inv_cn2[j] = 1.f / (sqrtf(cn2) + 1e-8f);
  }
  float lr[RR][4], mr[RR];
#pragma unroll
  for (int r = 0; r < RR; ++r) {
    float4 nr = *reinterpret_cast<const float4*>(
        noise_read + ((size_t)b * RR + r) * NN + c0);
    const float nrv[4] = {nr.x, nr.y, nr.z, nr.w};
    float m = -1e30f;
#pragma unroll
    for (int j = 0; j < 4; ++j) {
      float rd = omw[j] * rdM[r][j] + wtk[j] * rkwm[r];
      lr[r][j] = rd * invrk[r] * inv_cn2[j] + gumbelf(nrv[j]);
      m = fmaxf(m, lr[r][j]);
    }
    mr[r] = m;
  }
  block_max4(mr, s_red);
  float er[RR][4], ers[RR];
#pragma unroll
  for (int r = 0; r < RR; ++r) {
    float s = 0.f;
#pragma unroll
    for (int j = 0; j < 4; ++j) { er[r][j] = expf(lr[r][j] - mr[r]); s += er[r][j]; }
    ers[r] = s;
  }
  block_sum4(ers, s_red);
#pragma unroll
  for (int r = 0; r < RR; ++r) {
    const float inv_ers = 1.f / ers[r];
    float4 o;
    o.x = er[r][0] * inv_ers; o.y = er[r][1] * inv_ers;
    o.z = er[r][2] * inv_ers; o.w = er[r][3] * inv_ers;
    *reinterpret_cast<float4*>(read_wt_out + ((size_t)b * RR + r) * NN + c0) = o;
  }
}

// ---------------- K3: mem_new + m_erased + m_read over a 64-row half ----------------
__global__ __launch_bounds__(NT, 4) void k3_apply(
    const float* __restrict__ m_t, const float* __restrict__ memory,
    const float* __restrict__ wt_in, const float* __restrict__ read_wt,
    float* __restrict__ mem_new, float* __restrict__ m_read,
    float* __restrict__ m_erased)
{
  __shared__ float s_wm[WH];
  __shared__ float s_mr[WH * RR * NWAVE];  // [w_local][r][wave]
  __shared__ float s_me[WH * NWAVE];       // [w_local][wave]

  const int bid = blockIdx.x;
  const int b = bid >> 1, rh = bid & 1;
  const int tid = threadIdx.x;
  const int lane = tid & 63;
  const int wid = tid >> 6;
  const int c0 = 4 * tid;

  if (tid < WH) s_wm[tid] = tanhf(m_t[(size_t)b * WW + rh * WH + tid]);

  float wt[4], omw[4];
  {
    float4 w4 = *reinterpret_cast<const float4*>(wt_in + (size_t)b * NN + c0);
    wt[0] = w4.x; wt[1] = w4.y; wt[2] = w4.z; wt[3] = w4.w;
#pragma unroll
    for (int j = 0; j < 4; ++j) omw[j] = 1.f - wt[j];
  }
  float rwt[RR][4];
#pragma unroll
  for (int r = 0; r < RR; ++r) {
    float4 t = *reinterpret_cast<const float4*>(
        read_wt + ((size_t)b * RR + r) * NN + c0);
    rwt[r][0] = t.x; rwt[r][1] = t.y; rwt[r][2] = t.z; rwt[r][3] = t.w;
  }
  __syncthreads();

  const size_t hbase = (size_t)b * WW * NN + (size_t)rh * WH * NN;
  const float* Mb = memory + hbase;
  float* MNb = mem_new + hbase;

#pragma unroll 2
  for (int w0 = 0; w0 < WH; w0 += 4) {
    float pme[4], mrp[4][RR];
#pragma unroll
    for (int i = 0; i < 4; ++i) {
      const int w = w0 + i;
      const float wmw = s_wm[w];
      const size_t off = (size_t)w * NN + c0;
      float4 v = *reinterpret_cast<const float4*>(Mb + off);
      float4 nv;
      nv.x = fmaf(v.x, omw[0], wmw * wt[0]);
      nv.y = fmaf(v.y, omw[1], wmw * wt[1]);
      nv.z = fmaf(v.z, omw[2], wmw * wt[2]);
      nv.w = fmaf(v.w, omw[3], wmw * wt[3]);
      *reinterpret_cast<float4*>(MNb + off) = nv;
      float p = wt[0] * v.x;
      p = fmaf(wt[1], v.y, p);
      p = fmaf(wt[2], v.z, p);
      p = fmaf(wt[3], v.w, p);
      pme[i] = p;
#pragma unroll
      for (int r = 0; r < RR; ++r) {
        float a = rwt[r][0] * nv.x;
        a = fmaf(rwt[r][1], nv.y, a);
        a = fmaf(rwt[r][2], nv.z, a);
        a = fmaf(rwt[r][3], nv.w, a);
        mrp[i][r] = a;
      }
    }
    // 20 independent wave-reduction chains
#pragma unroll
    for (int m = 32; m >= 1; m >>= 1) {
#pragma unroll
      for (int i = 0; i < 4; ++i) {
        pme[i] += __shfl_xor(pme[i], m, 64);
#pragma unroll
        for (int r = 0; r < RR; ++r) mrp[i][r] += __shfl_xor(mrp[i][r], m, 64);
      }
    }
    if (lane == 0) {
#pragma unroll
      for (int i = 0; i < 4; ++i) {
        s_me[(w0 + i) * NWAVE + wid] = pme[i];
#pragma unroll
        for (int r = 0; r < RR; ++r)
          s_mr[((w0 + i) * RR + r) * NWAVE + wid] = mrp[i][r];
      }
    }
  }
  __syncthreads();

  if (tid < WH * RR) {                     // 256 threads: (w_local, r)
    const int wl = tid >> 2, r = tid & 3;
    float s = 0.f;
#pragma unroll
    for (int i = 0; i < NWAVE; ++i) s += s_mr[(wl * RR + r) * NWAVE + i];
    m_read[(size_t)b * RR * WW + r * WW + rh * WH + wl] = s;
  } else if (tid < WH * RR + WH) {         // 64 threads: w_local
    const int wl = tid - WH * RR;
    float s = 0.f;
#pragma unroll
    for (int i = 0; i < NWAVE; ++i) s += s_me[wl * NWAVE + i];
    m_erased[(size_t)b * WW + rh * WH + wl] = s;
  }
}

extern "C" void kernel_launch(void* const* d_in, const int* in_sizes, int n_in,
                              void* d_out, int out_size, void* d_ws, size_t ws_size,
                              hipStream_t stream) {
  (void)in_sizes; (void)n_in; (void)ws_size; (void)out_size;
  const float* k_r          = (const float*)d_in[0];
  const float* m_t          = (const float*)d_in[1];
  const float* hx           = (const float*)d_in[2];
  const float* memory       = (const float*)d_in[3];
  const float* usage        = (const float*)d_in[4];
  const float* read_weights = (const float*)d_in[5];
  const float* Wg           = (const float*)d_in[6];
  const float* bg           = (const float*)d_in[7];
  const float* noise_write  = (const float*)d_in[8];
  const float* noise_read   = (const float*)d_in[9];

  float* out       = (float*)d_out;
  float* m_read    = out;                                   // BS*RR*WW
  float* mem_new   = m_read + (size_t)BS * RR * WW;         // BS*WW*NN
  float* usage_new = mem_new + (size_t)BS * WW * NN;        // BS*NN
  float* read_wt   = usage_new + (size_t)BS * NN;           // BS*RR*NN
  float* m_erased  = read_wt + (size_t)BS * RR * NN;        // BS*WW

  float* stats = mem_new;            // 25.2 MB of partials, overwritten by K3
  float* wt_ws = (float*)d_ws;       // BS*NN floats = 2 MB write weights

  k1_stats<<<dim3(2 * BS), dim3(NT), 0, stream>>>(k_r, m_t, memory, stats);
  k2_softmax<<<dim3(BS), dim3(NT), 0, stream>>>(
      k_r, m_t, hx, usage, read_weights, Wg, bg, noise_write, noise_read,
      stats, wt_ws, usage_new, read_wt);
  k3_apply<<<dim3(2 * BS), dim3(NT), 0, stream>>>(
      m_t, memory, wt_ws, read_wt, mem_new, m_read, m_erased);
}

// Round 5
// 170.265 us; speedup vs baseline: 1.6585x; 1.0958x over previous
//
#include <hip/hip_runtime.h>

#define BS   256
#define RR   4
#define WW   128
#define NN   2048
#define HH   256
#define NT   512
#define WH   64            // rows per half-block (K1/K3)
#define NWAVE (NT / 64)
#define RPW  (WH / NWAVE)  // 8 rows per wave in K3

typedef float nfloat4 __attribute__((ext_vector_type(4)));

__device__ __forceinline__ float wave_sum(float v) {
#pragma unroll
  for (int m = 32; m >= 1; m >>= 1) v += __shfl_xor(v, m, 64);
  return v;
}
__device__ __forceinline__ float wave_max(float v) {
#pragma unroll
  for (int m = 32; m >= 1; m >>= 1) v = fmaxf(v, __shfl_xor(v, m, 64));
  return v;
}
__device__ __forceinline__ float block_sum(float v, float* s_red) {
  const int tid = threadIdx.x;
  v = wave_sum(v);
  __syncthreads();
  if ((tid & 63) == 0) s_red[tid >> 6] = v;
  __syncthreads();
  float s = s_red[0];
#pragma unroll
  for (int i = 1; i < NWAVE; ++i) s += s_red[i];
  return s;
}
__device__ __forceinline__ float block_max(float v, float* s_red) {
  const int tid = threadIdx.x;
  v = wave_max(v);
  __syncthreads();
  if ((tid & 63) == 0) s_red[tid >> 6] = v;
  __syncthreads();
  float s = s_red[0];
#pragma unroll
  for (int i = 1; i < NWAVE; ++i) s = fmaxf(s, s_red[i]);
  return s;
}
__device__ __forceinline__ void block_max4(float v[RR], float* s_red4) {
  const int tid = threadIdx.x, lane = tid & 63, wid = tid >> 6;
#pragma unroll
  for (int m = 32; m >= 1; m >>= 1) {
#pragma unroll
    for (int r = 0; r < RR; ++r) v[r] = fmaxf(v[r], __shfl_xor(v[r], m, 64));
  }
  __syncthreads();
  if (lane == 0) {
#pragma unroll
    for (int r = 0; r < RR; ++r) s_red4[wid * RR + r] = v[r];
  }
  __syncthreads();
#pragma unroll
  for (int r = 0; r < RR; ++r) {
    float s = s_red4[r];
#pragma unroll
    for (int i = 1; i < NWAVE; ++i) s = fmaxf(s, s_red4[i * RR + r]);
    v[r] = s;
  }
}
__device__ __forceinline__ void block_sum4(float v[RR], float* s_red4) {
  const int tid = threadIdx.x, lane = tid & 63, wid = tid >> 6;
#pragma unroll
  for (int m = 32; m >= 1; m >>= 1) {
#pragma unroll
    for (int r = 0; r < RR; ++r) v[r] += __shfl_xor(v[r], m, 64);
  }
  __syncthreads();
  if (lane == 0) {
#pragma unroll
    for (int r = 0; r < RR; ++r) s_red4[wid * RR + r] = v[r];
  }
  __syncthreads();
#pragma unroll
  for (int r = 0; r < RR; ++r) {
    float s = s_red4[r];
#pragma unroll
    for (int i = 1; i < NWAVE; ++i) s += s_red4[i * RR + r];
    v[r] = s;
  }
}
__device__ __forceinline__ float gumbelf(float u) {
  return -logf(-logf(u + 1e-10f) + 1e-10f);
}

// stats layout inside the mem_new output region (overwritten later by K3):
// comp 0=cn, 1=wd, 2..5=rdM[r];  index: ((rh*6+comp)*BS + b)*NN + n
#define STAT(base, rh, comp, b) ((base) + ((size_t)((rh)*6 + (comp)) * BS + (b)) * NN)

// ---------------- K1: per-column partial stats over a 64-row half ----------------
__global__ __launch_bounds__(NT, 4) void k1_stats(
    const float* __restrict__ k_r, const float* __restrict__ m_t,
    const float* __restrict__ memory, float* __restrict__ stats)
{
  __shared__ float s_wm[WH];
  __shared__ float s_rk[RR][WH];
  const int bid = blockIdx.x;
  const int b = bid >> 1, rh = bid & 1;
  const int tid = threadIdx.x;
  const int c0 = 4 * tid;

  if (tid < WH) {
    s_wm[tid] = tanhf(m_t[(size_t)b * WW + rh * WH + tid]);
  } else if (tid < WH + RR * WH) {
    const int i = tid - WH;            // 0..255: r = i>>6, w = i&63
    s_rk[i >> 6][i & 63] =
        tanhf(k_r[(size_t)b * RR * WW + (i >> 6) * WW + rh * WH + (i & 63)]);
  }
  __syncthreads();

  const float* Mb = memory + (size_t)b * WW * NN + (size_t)rh * WH * NN;
  float cn[4] = {0.f, 0.f, 0.f, 0.f}, wd[4] = {0.f, 0.f, 0.f, 0.f};
  float rdM[RR][4];
#pragma unroll
  for (int r = 0; r < RR; ++r) {
#pragma unroll
    for (int j = 0; j < 4; ++j) rdM[r][j] = 0.f;
  }
#pragma unroll 8
  for (int w = 0; w < WH; ++w) {
    float4 v = *reinterpret_cast<const float4*>(Mb + (size_t)w * NN + c0);
    const float wmw = s_wm[w];
    cn[0] = fmaf(v.x, v.x, cn[0]); wd[0] = fmaf(wmw, v.x, wd[0]);
    cn[1] = fmaf(v.y, v.y, cn[1]); wd[1] = fmaf(wmw, v.y, wd[1]);
    cn[2] = fmaf(v.z, v.z, cn[2]); wd[2] = fmaf(wmw, v.z, wd[2]);
    cn[3] = fmaf(v.w, v.w, cn[3]); wd[3] = fmaf(wmw, v.w, wd[3]);
#pragma unroll
    for (int r = 0; r < RR; ++r) {
      const float rkw = s_rk[r][w];
      rdM[r][0] = fmaf(rkw, v.x, rdM[r][0]);
      rdM[r][1] = fmaf(rkw, v.y, rdM[r][1]);
      rdM[r][2] = fmaf(rkw, v.z, rdM[r][2]);
      rdM[r][3] = fmaf(rkw, v.w, rdM[r][3]);
    }
  }
  float4 o;
  o.x = cn[0]; o.y = cn[1]; o.z = cn[2]; o.w = cn[3];
  *reinterpret_cast<float4*>(STAT(stats, rh, 0, b) + c0) = o;
  o.x = wd[0]; o.y = wd[1]; o.z = wd[2]; o.w = wd[3];
  *reinterpret_cast<float4*>(STAT(stats, rh, 1, b) + c0) = o;
#pragma unroll
  for (int r = 0; r < RR; ++r) {
    o.x = rdM[r][0]; o.y = rdM[r][1]; o.z = rdM[r][2]; o.w = rdM[r][3];
    *reinterpret_cast<float4*>(STAT(stats, rh, 2 + r, b) + c0) = o;
  }
}

// ---------------- K2: both softmaxes (one block per batch) ----------------
__global__ __launch_bounds__(NT) void k2_softmax(
    const float* __restrict__ k_r, const float* __restrict__ m_t,
    const float* __restrict__ hx, const float* __restrict__ usage,
    const float* __restrict__ read_weights, const float* __restrict__ Wg,
    const float* __restrict__ bg, const float* __restrict__ noise_write,
    const float* __restrict__ noise_read, const float* __restrict__ stats,
    float* __restrict__ wt_out, float* __restrict__ usage_new,
    float* __restrict__ read_wt_out)
{
  __shared__ float s_wm[WW];
  __shared__ float s_rk[RR * WW];
  __shared__ float s_red[NWAVE * RR];
  __shared__ float s_rkinv[RR], s_rkwm[RR];

  const int b = blockIdx.x;
  const int tid = threadIdx.x;
  const int lane = tid & 63;
  const int wid = tid >> 6;
  const int c0 = 4 * tid;

  float gp = 0.f;
  if (tid < HH) gp = hx[(size_t)b * HH + tid] * Wg[tid];
  if (tid < WW) s_wm[tid] = tanhf(m_t[(size_t)b * WW + tid]);
  s_rk[tid] = tanhf(k_r[(size_t)b * (RR * WW) + tid]);

  float ut[4];
  {
    const size_t rb = (size_t)b * RR * NN;
    float4 u4 = *reinterpret_cast<const float4*>(usage + (size_t)b * NN + c0);
    float4 r0 = *reinterpret_cast<const float4*>(read_weights + rb + c0);
    float4 r1 = *reinterpret_cast<const float4*>(read_weights + rb + NN + c0);
    float4 r2 = *reinterpret_cast<const float4*>(read_weights + rb + 2 * NN + c0);
    float4 r3 = *reinterpret_cast<const float4*>(read_weights + rb + 3 * NN + c0);
    ut[0] = 0.7f * u4.x + 0.3f * (r0.x + r1.x + r2.x + r3.x);
    ut[1] = 0.7f * u4.y + 0.3f * (r0.y + r1.y + r2.y + r3.y);
    ut[2] = 0.7f * u4.z + 0.3f * (r0.z + r1.z + r2.z + r3.z);
    ut[3] = 0.7f * u4.w + 0.3f * (r0.w + r1.w + r2.w + r3.w);
  }

  const float gamma = 1.f / (1.f + expf(-(block_sum(gp, s_red) + bg[0])));
  float wmp = (tid < WW) ? s_wm[tid] * s_wm[tid] : 0.f;
  const float wmss = block_sum(wmp, s_red);
  const float inv_wm = 1.f / (sqrtf(wmss) + 1e-8f);

  if (wid < RR) {
    const float a = s_rk[wid * WW + lane];
    const float c = s_rk[wid * WW + 64 + lane];
    const float wa = s_wm[lane], wc = s_wm[64 + lane];
    float ss = wave_sum(a * a + c * c);
    float sw = wave_sum(a * wa + c * wc);
    if (lane == 0) {
      s_rkinv[wid] = 1.f / (sqrtf(ss) + 1e-8f);
      s_rkwm[wid] = sw;
    }
  }
  __syncthreads();

  // combined column stats
  float cn[4], wd[4], rdM[RR][4];
  {
    float4 a0 = *reinterpret_cast<const float4*>(STAT(stats, 0, 0, b) + c0);
    float4 a1 = *reinterpret_cast<const float4*>(STAT(stats, 1, 0, b) + c0);
    cn[0] = a0.x + a1.x; cn[1] = a0.y + a1.y; cn[2] = a0.z + a1.z; cn[3] = a0.w + a1.w;
    float4 b0 = *reinterpret_cast<const float4*>(STAT(stats, 0, 1, b) + c0);
    float4 b1 = *reinterpret_cast<const float4*>(STAT(stats, 1, 1, b) + c0);
    wd[0] = b0.x + b1.x; wd[1] = b0.y + b1.y; wd[2] = b0.z + b1.z; wd[3] = b0.w + b1.w;
#pragma unroll
    for (int r = 0; r < RR; ++r) {
      float4 d0 = *reinterpret_cast<const float4*>(STAT(stats, 0, 2 + r, b) + c0);
      float4 d1 = *reinterpret_cast<const float4*>(STAT(stats, 1, 2 + r, b) + c0);
      rdM[r][0] = d0.x + d1.x; rdM[r][1] = d0.y + d1.y;
      rdM[r][2] = d0.z + d1.z; rdM[r][3] = d0.w + d1.w;
    }
  }

  // ---- write softmax ----
  float lg[4], mx = -1e30f;
  {
    float4 nw = *reinterpret_cast<const float4*>(noise_write + (size_t)b * NN + c0);
    const float nwv[4] = {nw.x, nw.y, nw.z, nw.w};
#pragma unroll
    for (int j = 0; j < 4; ++j) {
      float dist = wd[j] * inv_wm / (sqrtf(cn[j]) + 1e-8f);
      lg[j] = 1.f + dist - gamma * ut[j] + gumbelf(nwv[j]);
      mx = fmaxf(mx, lg[j]);
    }
  }
  mx = block_max(mx, s_red);
  float ex[4], es = 0.f;
#pragma unroll
  for (int j = 0; j < 4; ++j) { ex[j] = expf(lg[j] - mx); es += ex[j]; }
  es = block_sum(es, s_red);
  const float inv_es = 1.f / es;
  float wtk[4], omw[4];
#pragma unroll
  for (int j = 0; j < 4; ++j) { wtk[j] = ex[j] * inv_es; omw[j] = 1.f - wtk[j]; }
  {
    float4 un, wo;
    un.x = ut[0] * omw[0]; un.y = ut[1] * omw[1];
    un.z = ut[2] * omw[2]; un.w = ut[3] * omw[3];
    *reinterpret_cast<float4*>(usage_new + (size_t)b * NN + c0) = un;
    wo.x = wtk[0]; wo.y = wtk[1]; wo.z = wtk[2]; wo.w = wtk[3];
    *reinterpret_cast<float4*>(wt_out + (size_t)b * NN + c0) = wo;
  }

  // ---- read softmax (analytic stats of mem_new) ----
  const float invrk[RR] = { s_rkinv[0], s_rkinv[1], s_rkinv[2], s_rkinv[3] };
  const float rkwm[RR]  = { s_rkwm[0], s_rkwm[1], s_rkwm[2], s_rkwm[3] };
  float inv_cn2[4];
#pragma unroll
  for (int j = 0; j < 4; ++j) {
    float cn2 = omw[j] * omw[j] * cn[j]
              + 2.f * omw[j] * wtk[j] * wd[j]
              + wtk[j] * wtk[j] * wmss;
    inv_cn2[j] = 1.f / (sqrtf(cn2) + 1e-8f);
  }
  float lr[RR][4], mr[RR];
#pragma unroll
  for (int r = 0; r < RR; ++r) {
    float4 nr = *reinterpret_cast<const float4*>(
        noise_read + ((size_t)b * RR + r) * NN + c0);
    const float nrv[4] = {nr.x, nr.y, nr.z, nr.w};
    float m = -1e30f;
#pragma unroll
    for (int j = 0; j < 4; ++j) {
      float rd = omw[j] * rdM[r][j] + wtk[j] * rkwm[r];
      lr[r][j] = rd * invrk[r] * inv_cn2[j] + gumbelf(nrv[j]);
      m = fmaxf(m, lr[r][j]);
    }
    mr[r] = m;
  }
  block_max4(mr, s_red);
  float er[RR][4], ers[RR];
#pragma unroll
  for (int r = 0; r < RR; ++r) {
    float s = 0.f;
#pragma unroll
    for (int j = 0; j < 4; ++j) { er[r][j] = expf(lr[r][j] - mr[r]); s += er[r][j]; }
    ers[r] = s;
  }
  block_sum4(ers, s_red);
#pragma unroll
  for (int r = 0; r < RR; ++r) {
    const float inv_ers = 1.f / ers[r];
    float4 o;
    o.x = er[r][0] * inv_ers; o.y = er[r][1] * inv_ers;
    o.z = er[r][2] * inv_ers; o.w = er[r][3] * inv_ers;
    *reinterpret_cast<float4*>(read_wt_out + ((size_t)b * RR + r) * NN + c0) = o;
  }
}

// ---------------- K3: mem_new + m_erased + m_read, wave-owns-rows ----------------
__global__ __launch_bounds__(NT, 2) void k3_apply(
    const float* __restrict__ m_t, const float* __restrict__ memory,
    const float* __restrict__ wt_in, const float* __restrict__ read_wt,
    float* __restrict__ mem_new, float* __restrict__ m_read,
    float* __restrict__ m_erased)
{
  __shared__ float s_wt[NN];          // 8 KB  write weights
  __shared__ float s_rwt[RR][NN];     // 32 KB read weights

  const int bid = blockIdx.x;
  const int b = bid >> 1, rh = bid & 1;
  const int tid = threadIdx.x;
  const int lane = tid & 63;
  const int wid = tid >> 6;

  // stage weights into LDS (coalesced float4)
  {
    const int c = 4 * tid;
    float4 w4 = *reinterpret_cast<const float4*>(wt_in + (size_t)b * NN + c);
    *reinterpret_cast<float4*>(&s_wt[c]) = w4;
#pragma unroll
    for (int r = 0; r < RR; ++r) {
      float4 t = *reinterpret_cast<const float4*>(
          read_wt + ((size_t)b * RR + r) * NN + c);
      *reinterpret_cast<float4*>(&s_rwt[r][c]) = t;
    }
  }
  // this wave's 8 row keys
  const int w0 = wid * RPW;           // local row base within the 64-row half
  float wm[RPW];
#pragma unroll
  for (int i = 0; i < RPW; ++i)
    wm[i] = tanhf(m_t[(size_t)b * WW + rh * WH + w0 + i]);
  __syncthreads();

  const size_t hbase = (size_t)b * WW * NN + (size_t)rh * WH * NN;
  const float* Mb = memory + hbase;
  float* MNb = mem_new + hbase;

  float pme[RPW];
  float mrp[RPW][RR];
#pragma unroll
  for (int i = 0; i < RPW; ++i) {
    pme[i] = 0.f;
#pragma unroll
    for (int r = 0; r < RR; ++r) mrp[i][r] = 0.f;
  }

  // column chunks of 256 (64 lanes x float4); weights hoisted per chunk
#pragma unroll 1
  for (int ch = 0; ch < NN; ch += 256) {
    const int c = ch + 4 * lane;
    const float4 wt4 = *reinterpret_cast<const float4*>(&s_wt[c]);
    const float ow0 = 1.f - wt4.x, ow1 = 1.f - wt4.y,
                ow2 = 1.f - wt4.z, ow3 = 1.f - wt4.w;
    float4 rw[RR];
#pragma unroll
    for (int r = 0; r < RR; ++r)
      rw[r] = *reinterpret_cast<const float4*>(&s_rwt[r][c]);

#pragma unroll
    for (int i = 0; i < RPW; ++i) {
      const size_t off = (size_t)(w0 + i) * NN + c;
      float4 v = *reinterpret_cast<const float4*>(Mb + off);
      float4 nv;
      nv.x = fmaf(v.x, ow0, wm[i] * wt4.x);
      nv.y = fmaf(v.y, ow1, wm[i] * wt4.y);
      nv.z = fmaf(v.z, ow2, wm[i] * wt4.z);
      nv.w = fmaf(v.w, ow3, wm[i] * wt4.w);
      nfloat4 nvv;
      nvv.x = nv.x; nvv.y = nv.y; nvv.z = nv.z; nvv.w = nv.w;
      __builtin_nontemporal_store(nvv, reinterpret_cast<nfloat4*>(MNb + off));
      float p = wt4.x * v.x;
      p = fmaf(wt4.y, v.y, p);
      p = fmaf(wt4.z, v.z, p);
      p = fmaf(wt4.w, v.w, p);
      pme[i] += p;
#pragma unroll
      for (int r = 0; r < RR; ++r) {
        float a = rw[r].x * nv.x;
        a = fmaf(rw[r].y, nv.y, a);
        a = fmaf(rw[r].z, nv.z, a);
        a = fmaf(rw[r].w, nv.w, a);
        mrp[i][r] += a;
      }
    }
  }

  // reduce 40 accumulators across the wave (independent chains)
#pragma unroll
  for (int m = 32; m >= 1; m >>= 1) {
#pragma unroll
    for (int i = 0; i < RPW; ++i) {
      pme[i] += __shfl_xor(pme[i], m, 64);
#pragma unroll
      for (int r = 0; r < RR; ++r) mrp[i][r] += __shfl_xor(mrp[i][r], m, 64);
    }
  }
  if (lane == 0) {
    const int wg = rh * WH + w0;      // global row base
#pragma unroll
    for (int i = 0; i < RPW; ++i) {
      m_erased[(size_t)b * WW + wg + i] = pme[i];
#pragma unroll
      for (int r = 0; r < RR; ++r)
        m_read[(size_t)b * RR * WW + r * WW + wg + i] = mrp[i][r];
    }
  }
}

extern "C" void kernel_launch(void* const* d_in, const int* in_sizes, int n_in,
                              void* d_out, int out_size, void* d_ws, size_t ws_size,
                              hipStream_t stream) {
  (void)in_sizes; (void)n_in; (void)ws_size; (void)out_size;
  const float* k_r          = (const float*)d_in[0];
  const float* m_t          = (const float*)d_in[1];
  const float* hx           = (const float*)d_in[2];
  const float* memory       = (const float*)d_in[3];
  const float* usage        = (const float*)d_in[4];
  const float* read_weights = (const float*)d_in[5];
  const float* Wg           = (const float*)d_in[6];
  const float* bg           = (const float*)d_in[7];
  const float* noise_write  = (const float*)d_in[8];
  const float* noise_read   = (const float*)d_in[9];

  float* out       = (float*)d_out;
  float* m_read    = out;                                   // BS*RR*WW
  float* mem_new   = m_read + (size_t)BS * RR * WW;         // BS*WW*NN
  float* usage_new = mem_new + (size_t)BS * WW * NN;        // BS*NN
  float* read_wt   = usage_new + (size_t)BS * NN;           // BS*RR*NN
  float* m_erased  = read_wt + (size_t)BS * RR * NN;        // BS*WW

  float* stats = mem_new;            // 25.2 MB of partials, overwritten by K3
  float* wt_ws = (float*)d_ws;       // BS*NN floats = 2 MB write weights

  k1_stats<<<dim3(2 * BS), dim3(NT), 0, stream>>>(k_r, m_t, memory, stats);
  k2_softmax<<<dim3(BS), dim3(NT), 0, stream>>>(
      k_r, m_t, hx, usage, read_weights, Wg, bg, noise_write, noise_read,
      stats, wt_ws, usage_new, read_wt);
  k3_apply<<<dim3(2 * BS), dim3(NT), 0, stream>>>(
      m_t, memory, wt_ws, read_wt, mem_new, m_read, m_erased);
}